// Round 9
// baseline (568.422 us; speedup 1.0000x reference)
//
#include <hip/hip_runtime.h>
#include <hip/hip_bf16.h>
#include <math.h>
#include <stdint.h>

typedef __bf16 bf16_t;
typedef __attribute__((ext_vector_type(8))) __bf16 bf16x8;
typedef __attribute__((ext_vector_type(4))) float f32x4;
typedef float f32x4a __attribute__((ext_vector_type(4), aligned(4)));
typedef unsigned short u16;
typedef unsigned int u32;

#define DEV static __device__ __forceinline__
#define LOG2E 1.4426950408889634f

DEV u16 f2b(float f){ bf16_t h = (bf16_t)f; return __builtin_bit_cast(u16, h); }
DEV float b2f(u16 u){ bf16_t h = __builtin_bit_cast(bf16_t, u); return (float)h; }
DEV f32x4 mfma16(bf16x8 a, bf16x8 b, f32x4 c){
  return __builtin_amdgcn_mfma_f32_16x16x32_bf16(a, b, c, 0, 0, 0);
}

#if __has_builtin(__builtin_amdgcn_exp2f)
DEV float fexp2(float x){ return __builtin_amdgcn_exp2f(x); }
#else
DEV float fexp2(float x){ return exp2f(x); }
#endif

DEV void gld16(const void* g, void* l){
  __builtin_amdgcn_global_load_lds((const __attribute__((address_space(1))) u32*)g,
                                   (__attribute__((address_space(3))) u32*)l, 16, 0, 0);
}

DEV bf16x8 ldsA64(const u16* arr, int row, int ch){
  return *(const bf16x8*)&arr[row*64 + ((ch ^ (row&7))*8)];
}
DEV bf16x8 ldsA32(const u16* arr, int row, int ch){
  return *(const bf16x8*)&arr[row*32 + ((ch ^ ((row>>1)&3))*8)];
}

// ---------------- merged prep: convert_x (blocks 0..4095) + convert_w (4096..5119) + bias_table (5120..5375) ----------------
__global__ __launch_bounds__(256) void k_prep(const float* __restrict__ x,
                                              const float* __restrict__ Wq, const float* __restrict__ Wk,
                                              const float* __restrict__ Wv, const float* __restrict__ Wo,
                                              const float* __restrict__ rel_table, const float* __restrict__ mask,
                                              u16* __restrict__ xh, u16* __restrict__ xl,
                                              u16* __restrict__ wth, u16* __restrict__ wot,
                                              float* __restrict__ bt, float* __restrict__ bt2,
                                              float* __restrict__ msk2){
  __shared__ float tile[64][65];
  int bid = blockIdx.x;
  int t = threadIdx.x;
  if(bid < 4096){
    size_t i = ((size_t)bid*256 + t)*4;
    float4 v = *(const float4*)(x + i);
    ushort4 hv, lv; float f, hf;
    f=v.x; hv.x=f2b(f); hf=b2f(hv.x); lv.x=f2b(f-hf);
    f=v.y; hv.y=f2b(f); hf=b2f(hv.y); lv.y=f2b(f-hf);
    f=v.z; hv.z=f2b(f); hf=b2f(hv.z); lv.z=f2b(f-hf);
    f=v.w; hv.w=f2b(f); hf=b2f(hv.w); lv.w=f2b(f-hf);
    *(ushort4*)(xh+i) = hv;
    *(ushort4*)(xl+i) = lv;
  } else if(bid < 5120){
    int rr = bid - 4096;
    int z = rr >> 8, ky = (rr >> 4) & 15, nx = rr & 15;
    const float* W = (z==0)?Wq:((z==1)?Wk:((z==2)?Wv:Wo));
    int n0 = nx*64, k0 = ky*64;
    int r = t>>6, c = t&63;
    #pragma unroll
    for(int i=0;i<16;i++){
      int row = i*4 + r;
      tile[row][c] = W[(size_t)(k0+row)*1024 + n0 + c];
    }
    __syncthreads();
    #pragma unroll
    for(int i=0;i<16;i++){
      int nrow = i*4 + r;
      float v = tile[c][nrow];
      size_t o = (size_t)(n0+nrow)*1024 + k0 + c;
      if(z<3) wth[(size_t)z*1048576 + o] = f2b(v);
      else    wot[o] = f2b(v);
    }
  } else {
    int gid = (bid-5120)*256 + t;   // 16*4096
    if(gid < 4096) msk2[gid] = mask[gid]*LOG2E;
    int h = gid >> 12, idx = gid & 4095;
    float v = 0.f;
    if(idx < 4095){
      int delta = idx - 2047;   // k - q
      int n = -delta;
      int ret = 0;
      if(n < 0){ ret = 16; n = -n; }
      int bucket;
      if(n < 8) bucket = n + ret;
      else {
        float a = (float)log((double)n * 0.125);
        float rr2 = (float)((double)a / (double)2.7725887298583984f);
        int vl = 8 + (int)(rr2 * 8.0f);
        vl = vl > 15 ? 15 : vl;
        bucket = vl + ret;
      }
      v = rel_table[bucket*16 + h];
    }
    bt[gid] = v;
    bt2[gid] = v*LOG2E - 32.0f;
  }
}

// ---------------- QKV projection GEMM + overlaid position_bias write ----------------
// z 0..2: GEMM slices (Q 2-term, K/V 1-term). z==3: 256 blocks stream bias_out (HBM-bound,
// overlaps the compute-bound GEMM blocks which leave HBM idle).
__global__ __launch_bounds__(256) void k_gemm_qkv(const u16* __restrict__ xh, const u16* __restrict__ xl,
                                                  const u16* __restrict__ wth,
                                                  const float* __restrict__ bt, float* __restrict__ bias_out,
                                                  u16* __restrict__ qh, u16* __restrict__ ql,
                                                  u16* __restrict__ kh, u16* __restrict__ vt){
  __shared__ __align__(16) u16 SM[17408];
  int z = blockIdx.z;
  int t = threadIdx.x;
  if(z==3){
    // bias writer: 256 blocks x 1 MB
    int bid = blockIdx.y*8 + blockIdx.x;      // 0..255
    size_t basef = (size_t)bid*262144;
    for(int it=0; it<256; it++){
      size_t f = basef + (size_t)it*1024 + t*4;
      int h = (int)(f >> 22);
      int rem = (int)(f & 4194303);
      int q = rem >> 11;
      int k = rem & 2047;
      const float* row = bt + h*4096 + (k - q + 2047);
      float4 v = make_float4(row[0], row[1], row[2], row[3]);
      *(float4*)(bias_out + f) = v;
    }
    return;
  }
  u16* Ah = SM; u16* Al = SM+4096; u16* Bh = SM+8192;
  const u16* WH = wth + (size_t)z*1048576;
  int m0 = blockIdx.y*128, n0 = blockIdx.x*128;
  int w = t>>6, lane = t&63, l16 = lane&15, g = lane>>4;
  f32x4 acc[4][4];
  #pragma unroll
  for(int i=0;i<4;i++)
    #pragma unroll
    for(int j=0;j<4;j++) acc[i][j] = {0.f,0.f,0.f,0.f};
  int rbase = (w>>1)*64, cbase = (w&1)*64;
  for(int k0=0;k0<1024;k0+=32){
    __syncthreads();
    #pragma unroll
    for(int jj=0;jj<6;jj++){
      int q = w + 4*jj;            // chunk id 0..23: Ah 0-7, Al 8-15, Bh 16-23
      int arr = q>>3, sub = q&7;
      if(z!=0 && arr==1) continue;      // K,V: single-term, skip x-lo
      int row = sub*16 + (lane>>2);
      int lch = (lane&3) ^ ((row>>1)&3);
      const u16* src;
      if(arr==0)      src = xh + (size_t)(m0+row)*1024 + k0 + lch*8;
      else if(arr==1) src = xl + (size_t)(m0+row)*1024 + k0 + lch*8;
      else            src = WH + (size_t)(n0+row)*1024 + k0 + lch*8;
      gld16(src, &SM[q*512]);
    }
    __syncthreads();
    if(z!=0){
      bf16x8 ah[4];
      #pragma unroll
      for(int i=0;i<4;i++) ah[i] = ldsA32(Ah, rbase + i*16 + l16, g);
      #pragma unroll
      for(int j=0;j<4;j++){
        bf16x8 bh = ldsA32(Bh, cbase + j*16 + l16, g);
        #pragma unroll
        for(int i=0;i<4;i++)
          acc[i][j] = mfma16(ah[i], bh, acc[i][j]);
      }
    } else {
      bf16x8 ah[4], am[4];
      #pragma unroll
      for(int i=0;i<4;i++){
        int row = rbase + i*16 + l16;
        ah[i] = ldsA32(Ah, row, g);
        am[i] = ldsA32(Al, row, g);
      }
      #pragma unroll
      for(int j=0;j<4;j++){
        bf16x8 bh = ldsA32(Bh, cbase + j*16 + l16, g);
        #pragma unroll
        for(int i=0;i<4;i++){
          acc[i][j] = mfma16(ah[i], bh, acc[i][j]);
          acc[i][j] = mfma16(am[i], bh, acc[i][j]);
        }
      }
    }
  }
  if(z==2){
    // V: transpose via LDS (stride 136), coalesced 16B stores; vt [bh][d][s]
    __syncthreads();
    #pragma unroll
    for(int i=0;i<4;i++)
      #pragma unroll
      for(int j=0;j<4;j++)
        #pragma unroll
        for(int r=0;r<4;r++){
          int ml = rbase + i*16 + g*4 + r;
          int nl = cbase + j*16 + l16;
          SM[nl*136 + ml] = f2b(acc[i][j][r]);
        }
    __syncthreads();
    int bb = m0 >> 11;
    #pragma unroll
    for(int kk=0;kk<8;kk++){
      int id = t + 256*kk;
      int row = id>>4, ch = id&15;
      uint4 v = *(const uint4*)&SM[row*136 + ch*8];
      int n = n0 + row;
      size_t dst = ((size_t)(bb*16 + (n>>6))*64 + (n&63))*2048 + (m0&2047) + ch*8;
      *(uint4*)&vt[dst] = v;
    }
  } else {
    #pragma unroll
    for(int i=0;i<4;i++)
      #pragma unroll
      for(int j=0;j<4;j++)
        #pragma unroll
        for(int r=0;r<4;r++){
          int m = m0 + rbase + i*16 + g*4 + r;
          int n = n0 + cbase + j*16 + l16;
          float v = acc[i][j][r];
          if(z==0) v *= LOG2E;
          int b = m >> 11, s = m & 2047;
          int hh = n >> 6, d = n & 63;
          size_t a = ((size_t)(b*16+hh)*2048 + s)*64 + d;
          u16 hb = f2b(v);
          if(z==0){ qh[a]=hb; ql[a]=f2b(v - b2f(hb)); }
          else    { kh[a]=hb; }
        }
  }
}

// ---------------- flash attention (q-tile 64, full-K, max-free exp2) ----------------
// LDS: KH[0,4096) VT[4096,8192) PS 4 waves x 16x72 [8192,12800)
__global__ __launch_bounds__(256) void k_attn(const u16* __restrict__ qh, const u16* __restrict__ ql,
                                              const u16* __restrict__ kh,
                                              const u16* __restrict__ vt, const float* __restrict__ bt2,
                                              const float* __restrict__ msk2,
                                              u16* __restrict__ ao){
  __shared__ __align__(16) u16 SM[12800];
  u16* KH = SM; u16* VT = SM+4096;
  int bh = blockIdx.y, b = bh>>4, h = bh&15;
  int q0 = blockIdx.x*64;
  int t = threadIdx.x, w = t>>6, lane = t&63, l16 = lane&15, g = lane>>4;
  size_t base  = (size_t)bh*2048*64;   // q/k: [bh][s][64]
  size_t vbase = (size_t)bh*64*2048;   // v^T: [bh][d][s]
  u16* PSw = SM + 8192 + w*1152;
  const float* bt2h = bt2 + h*4096;
  const float* msk2b = msk2 + b*2048;

  // register-resident Q (pre-scaled by log2e): wave w owns q-rows q0+w*16..+15
  bf16x8 qfh[2], qfl[2];
  {
    int qr = q0 + w*16 + l16;
    size_t a0 = base + (size_t)qr*64 + g*8;
    qfh[0] = *(const bf16x8*)&qh[a0];
    qfl[0] = *(const bf16x8*)&ql[a0];
    qfh[1] = *(const bf16x8*)&qh[a0+32];
    qfl[1] = *(const bf16x8*)&ql[a0+32];
  }
  f32x4 O[4];
  float rs[4];
  #pragma unroll
  for(int jd=0;jd<4;jd++) O[jd] = {0.f,0.f,0.f,0.f};
  #pragma unroll
  for(int r=0;r<4;r++) rs[r] = 0.f;
  int qgbase = q0 + w*16 + g*4;

  for(int k0=0;k0<2048;k0+=64){
    __syncthreads();
    // stage KH/VT: 16 x 1KB DMA chunks, 4 per wave
    #pragma unroll
    for(int jj=0;jj<4;jj++){
      int q = w + 4*jj;
      int arr = q>>3, sub = q&7;
      int row = sub*8 + (lane>>3);
      int lch = (lane&7) ^ (row&7);
      const u16* src;
      if(arr==0) src = kh + base + (size_t)(k0+row)*64 + lch*8;
      else       src = vt + vbase + (size_t)row*2048 + k0 + lch*8;
      gld16(src, &SM[q*512]);
    }
    // bias + mask C-init (vector loads, reversed in-register; overlaps DMA wait)
    f32x4 sc[4];
    {
      const float* bb = bt2h + (k0 + l16 + 2047 - qgbase);
      #pragma unroll
      for(int j=0;j<4;j++){
        f32x4a ld = *(const f32x4a*)(bb + j*16 - 3);
        float mk = msk2b[k0 + j*16 + l16];
        sc[j] = (f32x4){ld[3]+mk, ld[2]+mk, ld[1]+mk, ld[0]+mk};
      }
    }
    __syncthreads();
    // QK^T, 2-term split (qh+ql vs kh)
    #pragma unroll
    for(int j=0;j<4;j++){
      int krow = j*16 + l16;
      bf16x8 kfh0 = ldsA64(KH, krow, g);
      bf16x8 kfh1 = ldsA64(KH, krow, 4+g);
      f32x4 s = sc[j];
      s = mfma16(qfh[0], kfh0, s);
      s = mfma16(qfl[0], kfh0, s);
      s = mfma16(qfh[1], kfh1, s);
      s = mfma16(qfl[1], kfh1, s);
      sc[j] = s;
    }
    // exp2, accumulate l, write P to LDS
    #pragma unroll
    for(int j=0;j<4;j++){
      #pragma unroll
      for(int r=0;r<4;r++){
        float p = fexp2(sc[j][r]);
        rs[r] += p;
        PSw[(g*4+r)*72 + j*16 + l16] = f2b(p);
      }
    }
    // PV (PS is wave-private, no barrier)
    #pragma unroll
    for(int ds=0; ds<2; ds++){
      bf16x8 pa = *(const bf16x8*)&PSw[l16*72 + ds*32 + g*8];
      #pragma unroll
      for(int jd=0;jd<4;jd++){
        bf16x8 vb = ldsA64(VT, jd*16 + l16, ds*4 + g);
        O[jd] = mfma16(pa, vb, O[jd]);
      }
    }
  }
  // epilogue: reduce rs within 16-lane groups, normalize, store bf16
  #pragma unroll
  for(int r=0;r<4;r++){
    float v = rs[r];
    v += __shfl_xor(v,1,64);
    v += __shfl_xor(v,2,64);
    v += __shfl_xor(v,4,64);
    v += __shfl_xor(v,8,64);
    float inv = 1.f/v;
    int q = qgbase + r;
    size_t a = ((size_t)(b*2048 + q))*1024 + h*64;
    #pragma unroll
    for(int jd=0;jd<4;jd++)
      ao[a + jd*16 + l16] = f2b(O[jd][r]*inv);
  }
}

// ---------------- output projection ----------------
__global__ __launch_bounds__(256) void k_gemm_out(const u16* __restrict__ ao, const u16* __restrict__ wot,
                                                  float* __restrict__ out){
  __shared__ __align__(16) u16 SM[8192];
  u16* As = SM; u16* Bs = SM+4096;
  int m0 = blockIdx.y*128, n0 = blockIdx.x*128;
  int t = threadIdx.x, w = t>>6, lane = t&63, l16 = lane&15, g = lane>>4;
  f32x4 acc[4][4];
  #pragma unroll
  for(int i=0;i<4;i++)
    #pragma unroll
    for(int j=0;j<4;j++) acc[i][j] = {0.f,0.f,0.f,0.f};
  int rbase = (w>>1)*64, cbase = (w&1)*64;
  for(int k0=0;k0<1024;k0+=32){
    __syncthreads();
    #pragma unroll
    for(int jj=0;jj<4;jj++){
      int q = w + 4*jj;
      int arr = q>>3, sub = q&7;
      int row = sub*16 + (lane>>2);
      int lch = (lane&3) ^ ((row>>1)&3);
      const u16* src;
      if(arr==0) src = ao  + (size_t)(m0+row)*1024 + k0 + lch*8;
      else       src = wot + (size_t)(n0+row)*1024 + k0 + lch*8;
      gld16(src, &SM[q*512]);
    }
    __syncthreads();
    bf16x8 af[4];
    #pragma unroll
    for(int i=0;i<4;i++) af[i] = ldsA32(As, rbase + i*16 + l16, g);
    #pragma unroll
    for(int j=0;j<4;j++){
      bf16x8 bfb = ldsA32(Bs, cbase + j*16 + l16, g);
      #pragma unroll
      for(int i=0;i<4;i++)
        acc[i][j] = mfma16(af[i], bfb, acc[i][j]);
    }
  }
  #pragma unroll
  for(int i=0;i<4;i++)
    #pragma unroll
    for(int j=0;j<4;j++)
      #pragma unroll
      for(int r=0;r<4;r++){
        int m = m0 + rbase + i*16 + g*4 + r;
        int n = n0 + cbase + j*16 + l16;
        out[(size_t)m*1024 + n] = acc[i][j][r];
      }
}

// ---------------- launch ----------------
extern "C" void kernel_launch(void* const* d_in, const int* in_sizes, int n_in,
                              void* d_out, int out_size, void* d_ws, size_t ws_size,
                              hipStream_t stream) {
  const float* x   = (const float*)d_in[0];
  const float* Wq  = (const float*)d_in[1];
  const float* Wk  = (const float*)d_in[2];
  const float* Wv  = (const float*)d_in[3];
  const float* Wo  = (const float*)d_in[4];
  const float* rel = (const float*)d_in[5];
  const float* msk = (const float*)d_in[6];
  float* out = (float*)d_out;
  float* bias_out = out + (size_t)4194304;
  char* ws = (char*)d_ws;
  u16* xh  = (u16*)(ws + 0);              // 8 MB
  u16* xl  = (u16*)(ws + 8388608);        // 8 MB
  u16* wth = (u16*)(ws + 16777216);       // 6 MB
  u16* wot = (u16*)(ws + 23068672);       // 2 MB
  u16* qh  = (u16*)(ws + 25165824);       // 8 MB
  u16* ql  = (u16*)(ws + 33554432);       // 8 MB
  u16* kh  = (u16*)(ws + 41943040);       // 8 MB
  u16* vt  = (u16*)(ws + 50331648);       // 8 MB (32 x 64 x 2048)
  u16* ao  = (u16*)(ws + 58720256);       // 8 MB
  float* bt  = (float*)(ws + 67108864);   // 256 KB
  float* bt2 = (float*)(ws + 67371008);   // 256 KB
  float* msk2= (float*)(ws + 67633152);   // 16 KB

  k_prep      <<<5376, 256, 0, stream>>>(x, Wq, Wk, Wv, Wo, rel, msk,
                                         xh, xl, wth, wot, bt, bt2, msk2);
  k_gemm_qkv  <<<dim3(8,32,4), 256, 0, stream>>>(xh, xl, wth, bt, bias_out, qh, ql, kh, vt);
  k_attn      <<<dim3(32,32), 256, 0, stream>>>(qh, ql, kh, vt, bt2, msk2, ao);
  k_gemm_out  <<<dim3(8,32), 256, 0, stream>>>(ao, wot, out);
}

// Round 10
// 481.276 us; speedup vs baseline: 1.1811x; 1.1811x over previous
//
#include <hip/hip_runtime.h>
#include <hip/hip_bf16.h>
#include <math.h>
#include <stdint.h>

typedef __bf16 bf16_t;
typedef __attribute__((ext_vector_type(8))) __bf16 bf16x8;
typedef __attribute__((ext_vector_type(4))) float f32x4;
typedef float f32x4a __attribute__((ext_vector_type(4), aligned(4)));
typedef unsigned short u16;
typedef unsigned int u32;

#define DEV static __device__ __forceinline__
#define LOG2E 1.4426950408889634f

DEV u16 f2b(float f){ bf16_t h = (bf16_t)f; return __builtin_bit_cast(u16, h); }
DEV float b2f(u16 u){ bf16_t h = __builtin_bit_cast(bf16_t, u); return (float)h; }
DEV f32x4 mfma16(bf16x8 a, bf16x8 b, f32x4 c){
  return __builtin_amdgcn_mfma_f32_16x16x32_bf16(a, b, c, 0, 0, 0);
}

#if __has_builtin(__builtin_amdgcn_exp2f)
DEV float fexp2(float x){ return __builtin_amdgcn_exp2f(x); }
#else
DEV float fexp2(float x){ return exp2f(x); }
#endif

DEV void gld16(const void* g, void* l){
  __builtin_amdgcn_global_load_lds((const __attribute__((address_space(1))) u32*)g,
                                   (__attribute__((address_space(3))) u32*)l, 16, 0, 0);
}

DEV bf16x8 ldsA64(const u16* arr, int row, int ch){
  return *(const bf16x8*)&arr[row*64 + ((ch ^ (row&7))*8)];
}
DEV bf16x8 ldsA32(const u16* arr, int row, int ch){
  return *(const bf16x8*)&arr[row*32 + ((ch ^ ((row>>1)&3))*8)];
}

// ---------------- merged prep: convert_x (blocks 0..4095) + convert_w (4096..5119) + bias_table (5120..5375) ----------------
__global__ __launch_bounds__(256) void k_prep(const float* __restrict__ x,
                                              const float* __restrict__ Wq, const float* __restrict__ Wk,
                                              const float* __restrict__ Wv, const float* __restrict__ Wo,
                                              const float* __restrict__ rel_table, const float* __restrict__ mask,
                                              u16* __restrict__ xh, u16* __restrict__ xl,
                                              u16* __restrict__ wth, u16* __restrict__ wot,
                                              float* __restrict__ bt, float* __restrict__ bt2,
                                              float* __restrict__ msk2){
  __shared__ float tile[64][65];
  int bid = blockIdx.x;
  int t = threadIdx.x;
  if(bid < 4096){
    size_t i = ((size_t)bid*256 + t)*4;
    float4 v = *(const float4*)(x + i);
    ushort4 hv, lv; float f, hf;
    f=v.x; hv.x=f2b(f); hf=b2f(hv.x); lv.x=f2b(f-hf);
    f=v.y; hv.y=f2b(f); hf=b2f(hv.y); lv.y=f2b(f-hf);
    f=v.z; hv.z=f2b(f); hf=b2f(hv.z); lv.z=f2b(f-hf);
    f=v.w; hv.w=f2b(f); hf=b2f(hv.w); lv.w=f2b(f-hf);
    *(ushort4*)(xh+i) = hv;
    *(ushort4*)(xl+i) = lv;
  } else if(bid < 5120){
    int rr = bid - 4096;
    int z = rr >> 8, ky = (rr >> 4) & 15, nx = rr & 15;
    const float* W = (z==0)?Wq:((z==1)?Wk:((z==2)?Wv:Wo));
    int n0 = nx*64, k0 = ky*64;
    int r = t>>6, c = t&63;
    #pragma unroll
    for(int i=0;i<16;i++){
      int row = i*4 + r;
      tile[row][c] = W[(size_t)(k0+row)*1024 + n0 + c];
    }
    __syncthreads();
    #pragma unroll
    for(int i=0;i<16;i++){
      int nrow = i*4 + r;
      float v = tile[c][nrow];
      size_t o = (size_t)(n0+nrow)*1024 + k0 + c;
      if(z<3) wth[(size_t)z*1048576 + o] = f2b(v);
      else    wot[o] = f2b(v);
    }
  } else {
    int gid = (bid-5120)*256 + t;   // 16*4096
    if(gid < 4096) msk2[gid] = mask[gid]*LOG2E;
    int h = gid >> 12, idx = gid & 4095;
    float v = 0.f;
    if(idx < 4095){
      int delta = idx - 2047;   // k - q
      int n = -delta;
      int ret = 0;
      if(n < 0){ ret = 16; n = -n; }
      int bucket;
      if(n < 8) bucket = n + ret;
      else {
        float a = (float)log((double)n * 0.125);
        float rr2 = (float)((double)a / (double)2.7725887298583984f);
        int vl = 8 + (int)(rr2 * 8.0f);
        vl = vl > 15 ? 15 : vl;
        bucket = vl + ret;
      }
      v = rel_table[bucket*16 + h];
    }
    bt[gid] = v;
    bt2[gid] = v*LOG2E - 32.0f;
  }
}

// ---------------- QKV projection GEMM (R8-proven) ----------------
// Q: 2-term ((xh+xl)*Wh); K,V: 1-term (xh*Wh)
__global__ __launch_bounds__(256) void k_gemm_qkv(const u16* __restrict__ xh, const u16* __restrict__ xl,
                                                  const u16* __restrict__ wth,
                                                  u16* __restrict__ qh, u16* __restrict__ ql,
                                                  u16* __restrict__ kh, u16* __restrict__ vt){
  __shared__ __align__(16) u16 SM[17408];
  u16* Ah = SM; u16* Al = SM+4096; u16* Bh = SM+8192;
  int z = blockIdx.z;
  const u16* WH = wth + (size_t)z*1048576;
  int m0 = blockIdx.y*128, n0 = blockIdx.x*128;
  int t = threadIdx.x, w = t>>6, lane = t&63, l16 = lane&15, g = lane>>4;
  f32x4 acc[4][4];
  #pragma unroll
  for(int i=0;i<4;i++)
    #pragma unroll
    for(int j=0;j<4;j++) acc[i][j] = {0.f,0.f,0.f,0.f};
  int rbase = (w>>1)*64, cbase = (w&1)*64;
  for(int k0=0;k0<1024;k0+=32){
    __syncthreads();
    #pragma unroll
    for(int jj=0;jj<6;jj++){
      int q = w + 4*jj;            // chunk id 0..23: Ah 0-7, Al 8-15, Bh 16-23
      int arr = q>>3, sub = q&7;
      if(z!=0 && arr==1) continue;      // K,V: single-term, skip x-lo
      int row = sub*16 + (lane>>2);
      int lch = (lane&3) ^ ((row>>1)&3);
      const u16* src;
      if(arr==0)      src = xh + (size_t)(m0+row)*1024 + k0 + lch*8;
      else if(arr==1) src = xl + (size_t)(m0+row)*1024 + k0 + lch*8;
      else            src = WH + (size_t)(n0+row)*1024 + k0 + lch*8;
      gld16(src, &SM[q*512]);
    }
    __syncthreads();
    if(z!=0){
      bf16x8 ah[4];
      #pragma unroll
      for(int i=0;i<4;i++) ah[i] = ldsA32(Ah, rbase + i*16 + l16, g);
      #pragma unroll
      for(int j=0;j<4;j++){
        bf16x8 bh = ldsA32(Bh, cbase + j*16 + l16, g);
        #pragma unroll
        for(int i=0;i<4;i++)
          acc[i][j] = mfma16(ah[i], bh, acc[i][j]);
      }
    } else {
      bf16x8 ah[4], am[4];
      #pragma unroll
      for(int i=0;i<4;i++){
        int row = rbase + i*16 + l16;
        ah[i] = ldsA32(Ah, row, g);
        am[i] = ldsA32(Al, row, g);
      }
      #pragma unroll
      for(int j=0;j<4;j++){
        bf16x8 bh = ldsA32(Bh, cbase + j*16 + l16, g);
        #pragma unroll
        for(int i=0;i<4;i++){
          acc[i][j] = mfma16(ah[i], bh, acc[i][j]);
          acc[i][j] = mfma16(am[i], bh, acc[i][j]);
        }
      }
    }
  }
  if(z==2){
    // V: transpose via LDS (stride 136), coalesced 16B stores; vt [bh][d][s]
    __syncthreads();
    #pragma unroll
    for(int i=0;i<4;i++)
      #pragma unroll
      for(int j=0;j<4;j++)
        #pragma unroll
        for(int r=0;r<4;r++){
          int ml = rbase + i*16 + g*4 + r;
          int nl = cbase + j*16 + l16;
          SM[nl*136 + ml] = f2b(acc[i][j][r]);
        }
    __syncthreads();
    int bb = m0 >> 11;
    #pragma unroll
    for(int kk=0;kk<8;kk++){
      int id = t + 256*kk;
      int row = id>>4, ch = id&15;
      uint4 v = *(const uint4*)&SM[row*136 + ch*8];
      int n = n0 + row;
      size_t dst = ((size_t)(bb*16 + (n>>6))*64 + (n&63))*2048 + (m0&2047) + ch*8;
      *(uint4*)&vt[dst] = v;
    }
  } else {
    #pragma unroll
    for(int i=0;i<4;i++)
      #pragma unroll
      for(int j=0;j<4;j++)
        #pragma unroll
        for(int r=0;r<4;r++){
          int m = m0 + rbase + i*16 + g*4 + r;
          int n = n0 + cbase + j*16 + l16;
          float v = acc[i][j][r];
          if(z==0) v *= LOG2E;
          int b = m >> 11, s = m & 2047;
          int hh = n >> 6, d = n & 63;
          size_t a = ((size_t)(b*16+hh)*2048 + s)*64 + d;
          u16 hb = f2b(v);
          if(z==0){ qh[a]=hb; ql[a]=f2b(v - b2f(hb)); }
          else    { kh[a]=hb; }
        }
  }
}

// ---------------- flash attention + distributed position_bias write ----------------
// Each block writes 2048 contiguous floats of bias_out per k-iter (32 iters x 1024 blocks = 256 MB),
// hiding the HBM write under the LDS/issue-bound attention loop.
// LDS: KH[0,4096) VT[4096,8192) PS 4 waves x 16x72 [8192,12800)
__global__ __launch_bounds__(256) void k_attn(const u16* __restrict__ qh, const u16* __restrict__ ql,
                                              const u16* __restrict__ kh,
                                              const u16* __restrict__ vt, const float* __restrict__ bt2,
                                              const float* __restrict__ msk2,
                                              const float* __restrict__ bt, float* __restrict__ bias_out,
                                              u16* __restrict__ ao){
  __shared__ __align__(16) u16 SM[12800];
  u16* KH = SM; u16* VT = SM+4096;
  int bh = blockIdx.y, b = bh>>4, h = bh&15;
  int q0 = blockIdx.x*64;
  int t = threadIdx.x, w = t>>6, lane = t&63, l16 = lane&15, g = lane>>4;
  size_t base  = (size_t)bh*2048*64;   // q/k: [bh][s][64]
  size_t vbase = (size_t)bh*64*2048;   // v^T: [bh][d][s]
  u16* PSw = SM + 8192 + w*1152;
  const float* bt2h = bt2 + h*4096;
  const float* msk2b = msk2 + b*2048;
  size_t wbase = ((size_t)(bh*32 + blockIdx.x))*65536 + t*8;   // this block's bias_out slice

  // register-resident Q (pre-scaled by log2e): wave w owns q-rows q0+w*16..+15
  bf16x8 qfh[2], qfl[2];
  {
    int qr = q0 + w*16 + l16;
    size_t a0 = base + (size_t)qr*64 + g*8;
    qfh[0] = *(const bf16x8*)&qh[a0];
    qfl[0] = *(const bf16x8*)&ql[a0];
    qfh[1] = *(const bf16x8*)&qh[a0+32];
    qfl[1] = *(const bf16x8*)&ql[a0+32];
  }
  f32x4 O[4];
  float rs[4];
  #pragma unroll
  for(int jd=0;jd<4;jd++) O[jd] = {0.f,0.f,0.f,0.f};
  #pragma unroll
  for(int r=0;r<4;r++) rs[r] = 0.f;
  int qgbase = q0 + w*16 + g*4;

  for(int k0=0;k0<2048;k0+=64){
    __syncthreads();
    // stage KH/VT: 16 x 1KB DMA chunks, 4 per wave
    #pragma unroll
    for(int jj=0;jj<4;jj++){
      int q = w + 4*jj;
      int arr = q>>3, sub = q&7;
      int row = sub*8 + (lane>>3);
      int lch = (lane&7) ^ (row&7);
      const u16* src;
      if(arr==0) src = kh + base + (size_t)(k0+row)*64 + lch*8;
      else       src = vt + vbase + (size_t)row*2048 + k0 + lch*8;
      gld16(src, &SM[q*512]);
    }
    // distributed bias_out write: 8 floats/thread/iter (gather from L2-hot bt, coalesced store)
    {
      size_t f = wbase + (size_t)(k0>>6)*2048;
      int hh = (int)(f >> 22);
      int rem = (int)(f & 4194303);
      int qq = rem >> 11;
      int kk = rem & 2047;
      const float* row = bt + hh*4096 + (kk - qq + 2047);
      f32x4a v0 = *(const f32x4a*)(row);
      f32x4a v1 = *(const f32x4a*)(row + 4);
      *(f32x4a*)(bias_out + f)     = v0;
      *(f32x4a*)(bias_out + f + 4) = v1;
    }
    // bias + mask C-init (vector loads, reversed in-register; overlaps DMA wait)
    f32x4 sc[4];
    {
      const float* bb = bt2h + (k0 + l16 + 2047 - qgbase);
      #pragma unroll
      for(int j=0;j<4;j++){
        f32x4a ld = *(const f32x4a*)(bb + j*16 - 3);
        float mk = msk2b[k0 + j*16 + l16];
        sc[j] = (f32x4){ld[3]+mk, ld[2]+mk, ld[1]+mk, ld[0]+mk};
      }
    }
    __syncthreads();
    // QK^T, 2-term split (qh+ql vs kh)
    #pragma unroll
    for(int j=0;j<4;j++){
      int krow = j*16 + l16;
      bf16x8 kfh0 = ldsA64(KH, krow, g);
      bf16x8 kfh1 = ldsA64(KH, krow, 4+g);
      f32x4 s = sc[j];
      s = mfma16(qfh[0], kfh0, s);
      s = mfma16(qfl[0], kfh0, s);
      s = mfma16(qfh[1], kfh1, s);
      s = mfma16(qfl[1], kfh1, s);
      sc[j] = s;
    }
    // exp2, accumulate l, write P to LDS
    #pragma unroll
    for(int j=0;j<4;j++){
      #pragma unroll
      for(int r=0;r<4;r++){
        float p = fexp2(sc[j][r]);
        rs[r] += p;
        PSw[(g*4+r)*72 + j*16 + l16] = f2b(p);
      }
    }
    // PV (PS is wave-private, no barrier)
    #pragma unroll
    for(int ds=0; ds<2; ds++){
      bf16x8 pa = *(const bf16x8*)&PSw[l16*72 + ds*32 + g*8];
      #pragma unroll
      for(int jd=0;jd<4;jd++){
        bf16x8 vb = ldsA64(VT, jd*16 + l16, ds*4 + g);
        O[jd] = mfma16(pa, vb, O[jd]);
      }
    }
  }
  // epilogue: reduce rs within 16-lane groups, normalize, store bf16
  #pragma unroll
  for(int r=0;r<4;r++){
    float v = rs[r];
    v += __shfl_xor(v,1,64);
    v += __shfl_xor(v,2,64);
    v += __shfl_xor(v,4,64);
    v += __shfl_xor(v,8,64);
    float inv = 1.f/v;
    int q = qgbase + r;
    size_t a = ((size_t)(b*2048 + q))*1024 + h*64;
    #pragma unroll
    for(int jd=0;jd<4;jd++)
      ao[a + jd*16 + l16] = f2b(O[jd][r]*inv);
  }
}

// ---------------- output projection ----------------
__global__ __launch_bounds__(256) void k_gemm_out(const u16* __restrict__ ao, const u16* __restrict__ wot,
                                                  float* __restrict__ out){
  __shared__ __align__(16) u16 SM[8192];
  u16* As = SM; u16* Bs = SM+4096;
  int m0 = blockIdx.y*128, n0 = blockIdx.x*128;
  int t = threadIdx.x, w = t>>6, lane = t&63, l16 = lane&15, g = lane>>4;
  f32x4 acc[4][4];
  #pragma unroll
  for(int i=0;i<4;i++)
    #pragma unroll
    for(int j=0;j<4;j++) acc[i][j] = {0.f,0.f,0.f,0.f};
  int rbase = (w>>1)*64, cbase = (w&1)*64;
  for(int k0=0;k0<1024;k0+=32){
    __syncthreads();
    #pragma unroll
    for(int jj=0;jj<4;jj++){
      int q = w + 4*jj;
      int arr = q>>3, sub = q&7;
      int row = sub*16 + (lane>>2);
      int lch = (lane&3) ^ ((row>>1)&3);
      const u16* src;
      if(arr==0) src = ao  + (size_t)(m0+row)*1024 + k0 + lch*8;
      else       src = wot + (size_t)(n0+row)*1024 + k0 + lch*8;
      gld16(src, &SM[q*512]);
    }
    __syncthreads();
    bf16x8 af[4];
    #pragma unroll
    for(int i=0;i<4;i++) af[i] = ldsA32(As, rbase + i*16 + l16, g);
    #pragma unroll
    for(int j=0;j<4;j++){
      bf16x8 bfb = ldsA32(Bs, cbase + j*16 + l16, g);
      #pragma unroll
      for(int i=0;i<4;i++)
        acc[i][j] = mfma16(af[i], bfb, acc[i][j]);
    }
  }
  #pragma unroll
  for(int i=0;i<4;i++)
    #pragma unroll
    for(int j=0;j<4;j++)
      #pragma unroll
      for(int r=0;r<4;r++){
        int m = m0 + rbase + i*16 + g*4 + r;
        int n = n0 + cbase + j*16 + l16;
        out[(size_t)m*1024 + n] = acc[i][j][r];
      }
}

// ---------------- launch ----------------
extern "C" void kernel_launch(void* const* d_in, const int* in_sizes, int n_in,
                              void* d_out, int out_size, void* d_ws, size_t ws_size,
                              hipStream_t stream) {
  const float* x   = (const float*)d_in[0];
  const float* Wq  = (const float*)d_in[1];
  const float* Wk  = (const float*)d_in[2];
  const float* Wv  = (const float*)d_in[3];
  const float* Wo  = (const float*)d_in[4];
  const float* rel = (const float*)d_in[5];
  const float* msk = (const float*)d_in[6];
  float* out = (float*)d_out;
  float* bias_out = out + (size_t)4194304;
  char* ws = (char*)d_ws;
  u16* xh  = (u16*)(ws + 0);              // 8 MB
  u16* xl  = (u16*)(ws + 8388608);        // 8 MB
  u16* wth = (u16*)(ws + 16777216);       // 6 MB
  u16* wot = (u16*)(ws + 23068672);       // 2 MB
  u16* qh  = (u16*)(ws + 25165824);       // 8 MB
  u16* ql  = (u16*)(ws + 33554432);       // 8 MB
  u16* kh  = (u16*)(ws + 41943040);       // 8 MB
  u16* vt  = (u16*)(ws + 50331648);       // 8 MB (32 x 64 x 2048)
  u16* ao  = (u16*)(ws + 58720256);       // 8 MB
  float* bt  = (float*)(ws + 67108864);   // 256 KB
  float* bt2 = (float*)(ws + 67371008);   // 256 KB
  float* msk2= (float*)(ws + 67633152);   // 16 KB

  k_prep      <<<5376, 256, 0, stream>>>(x, Wq, Wk, Wv, Wo, rel, msk,
                                         xh, xl, wth, wot, bt, bt2, msk2);
  k_gemm_qkv  <<<dim3(8,32,3), 256, 0, stream>>>(xh, xl, wth, qh, ql, kh, vt);
  k_attn      <<<dim3(32,32), 256, 0, stream>>>(qh, ql, kh, vt, bt2, msk2, bt, bias_out, ao);
  k_gemm_out  <<<dim3(8,32), 256, 0, stream>>>(ao, wot, out);
}